// Round 1
// baseline (2310.515 us; speedup 1.0000x reference)
//
#include <hip/hip_runtime.h>
#include <cstdint>
#include <cstring>

typedef _Float16 f16;
typedef _Float16 f16x8 __attribute__((ext_vector_type(8)));
typedef float f32x4 __attribute__((ext_vector_type(4)));

// ---- JAX threefry scheme: 1 = partitionable (jax >= 0.4.36 default), 0 = original
static constexpr int kPartitionable = 1;

// ---------------- Threefry-2x32 (host + device) ----------------
__host__ __device__ inline void tf2x32(uint32_t k0, uint32_t k1,
                                       uint32_t x0, uint32_t x1,
                                       uint32_t& o0, uint32_t& o1) {
  uint32_t ks[3] = {k0, k1, k0 ^ k1 ^ 0x1BD11BDAu};
  uint32_t v0 = x0 + ks[0], v1 = x1 + ks[1];
  const int r0[4] = {13, 15, 26, 6};
  const int r1[4] = {17, 29, 16, 24};
  for (int g = 0; g < 5; ++g) {
    const int* rr = (g & 1) ? r1 : r0;
    for (int j = 0; j < 4; ++j) {
      v0 += v1;
      v1 = (v1 << rr[j]) | (v1 >> (32 - rr[j]));
      v1 ^= v0;
    }
    v0 += ks[(g + 1) % 3];
    v1 += ks[(g + 2) % 3] + (uint32_t)(g + 1);
  }
  o0 = v0; o1 = v1;
}

// ---------------- split-fp16 MFMA GEMM ----------------
// C[m][n] = sum_k A[m][k]*Bt[n][k], A/Bt given as (hi,lo) fp16 pairs.
// 3 MFMAs per fragment pair: hi*hi + hi*lo + lo*hi (fp32 accumulate).
// Epilogue: +bias1(+bias2), optional relu; writes f32 OR fp16 (hi,lo) split.
template <int BM, int BN>
__global__ __launch_bounds__(256, 2) void gemm_split(
    const f16* __restrict__ Ah, const f16* __restrict__ Al, int lda,
    const f16* __restrict__ Bh, const f16* __restrict__ Bl, int ldb,
    int K,
    const float* __restrict__ bias1, const float* __restrict__ bias2,
    int nReal, int relu, int writeF32,
    float* __restrict__ outF, f16* __restrict__ outH, f16* __restrict__ outL,
    int ldo) {
  constexpr int BK = 64;
  constexpr int TM = BM / 32;  // 16x16 tiles per wave along M
  constexpr int TN = BN / 32;
  static_assert(BM == BN, "square tiles only");
  __shared__ f16 sAh[BM * BK];
  __shared__ f16 sAl[BM * BK];
  __shared__ f16 sBh[BN * BK];
  __shared__ f16 sBl[BN * BK];

  const int tid = threadIdx.x;
  const int wave = tid >> 6;
  const int lane = tid & 63;
  const int wm = wave & 1, wn = wave >> 1;
  const int m0 = blockIdx.x * BM;
  const int n0 = blockIdx.y * BN;

  f32x4 acc[TM][TN];
  const f32x4 zero = {0.f, 0.f, 0.f, 0.f};
#pragma unroll
  for (int i = 0; i < TM; ++i)
#pragma unroll
    for (int j = 0; j < TN; ++j) acc[i][j] = zero;

  // staging: wave 0->sAh, 1->sAl, 2->sBh, 3->sBl   (BM==BN so same shape)
  const f16* src;
  f16* dst;
  int ld, base;
  if (wave == 0)      { src = Ah; dst = sAh; ld = lda; base = m0; }
  else if (wave == 1) { src = Al; dst = sAl; ld = lda; base = m0; }
  else if (wave == 2) { src = Bh; dst = sBh; ld = ldb; base = n0; }
  else                { src = Bl; dst = sBl; ld = ldb; base = n0; }
  constexpr int NITER = (BM * 8) / 64;  // 16B chunks per lane per tile

  for (int k0 = 0; k0 < K; k0 += BK) {
    __syncthreads();
#pragma unroll
    for (int j = 0; j < NITER; ++j) {
      int c = j * 64 + lane;
      int row = c >> 3, col = c & 7;
      const uint4* g = (const uint4*)(src + (size_t)(base + row) * ld + k0) + col;
      uint4 v = *g;
      ((uint4*)dst)[c] = v;
    }
    __syncthreads();
#pragma unroll
    for (int kk = 0; kk < BK; kk += 32) {
      const int fr = lane & 15;
      const int q8 = (lane >> 4) * 8;
      f16x8 aH[TM], aL[TM], bH[TN], bL[TN];
#pragma unroll
      for (int i = 0; i < TM; ++i) {
        int off = (wm * (BM / 2) + i * 16 + fr) * BK + kk + q8;
        aH[i] = *(const f16x8*)&sAh[off];
        aL[i] = *(const f16x8*)&sAl[off];
      }
#pragma unroll
      for (int j = 0; j < TN; ++j) {
        int off = (wn * (BN / 2) + j * 16 + fr) * BK + kk + q8;
        bH[j] = *(const f16x8*)&sBh[off];
        bL[j] = *(const f16x8*)&sBl[off];
      }
#pragma unroll
      for (int i = 0; i < TM; ++i)
#pragma unroll
        for (int j = 0; j < TN; ++j) {
          acc[i][j] = __builtin_amdgcn_mfma_f32_16x16x32_f16(aH[i], bH[j], acc[i][j], 0, 0, 0);
          acc[i][j] = __builtin_amdgcn_mfma_f32_16x16x32_f16(aH[i], bL[j], acc[i][j], 0, 0, 0);
          acc[i][j] = __builtin_amdgcn_mfma_f32_16x16x32_f16(aL[i], bH[j], acc[i][j], 0, 0, 0);
        }
    }
  }
  // epilogue: C/D layout col=lane&15, row=(lane>>4)*4+reg (m89/m91 verified)
  const int rq = lane >> 4, cl = lane & 15;
#pragma unroll
  for (int i = 0; i < TM; ++i)
#pragma unroll
    for (int j = 0; j < TN; ++j)
#pragma unroll
      for (int r = 0; r < 4; ++r) {
        int row = m0 + wm * (BM / 2) + i * 16 + rq * 4 + r;
        int col = n0 + wn * (BN / 2) + j * 16 + cl;
        float v = acc[i][j][r];
        if (col < nReal) {
          if (bias1) v += bias1[col];
          if (bias2) v += bias2[col];
          if (relu) v = fmaxf(v, 0.f);
        } else {
          v = 0.f;
        }
        size_t o = (size_t)row * ldo + col;
        if (writeF32) {
          outF[o] = v;
        } else {
          f16 h = (f16)v;
          outH[o] = h;
          outL[o] = (f16)(v - (float)h);
        }
      }
}

// ---------------- conversion kernels ----------------
// feats = [actual | objective | last_action | ep | zeros]  -> hi/lo fp16 [4096][9280]
__global__ void conv_feats(const float* __restrict__ A, const float* __restrict__ O,
                           const float* __restrict__ LA, const int* __restrict__ EP,
                           f16* __restrict__ H, f16* __restrict__ L) {
  uint32_t idx = blockIdx.x * 256u + threadIdx.x;
  const uint32_t total = 4096u * 9280u;
  if (idx >= total) return;
  uint32_t b = idx / 9280u, c = idx - b * 9280u;
  float v;
  if (c < 4608u) v = A[(size_t)b * 4608 + c];
  else if (c < 9216u) v = O[(size_t)b * 4608 + (c - 4608u)];
  else if (c < 9224u) v = LA[(size_t)b * 8 + (c - 9216u)];
  else if (c == 9224u) v = (float)EP[0];
  else v = 0.f;
  f16 h = (f16)v;
  H[idx] = h;
  L[idx] = (f16)(v - (float)h);
}

// W [Kreal][Nreal] (row stride Nreal) -> Bt hi/lo [Npad][Kpad] with Bt[n][k]=W[k][n]
__global__ void convT_kernel(const float* __restrict__ W, int Kreal, int Nreal,
                             f16* __restrict__ BtH, f16* __restrict__ BtL, int Kpad) {
  __shared__ float tile[32][33];
  int k0 = blockIdx.x * 32, n0 = blockIdx.y * 32;
  int tx = threadIdx.x, ty = threadIdx.y;  // 32 x 8
  for (int r = 0; r < 32; r += 8) {
    int k = k0 + ty + r, n = n0 + tx;
    float v = (k < Kreal && n < Nreal) ? W[(size_t)k * Nreal + n] : 0.f;
    tile[ty + r][tx] = v;
  }
  __syncthreads();
  for (int r = 0; r < 32; r += 8) {
    int n = n0 + ty + r, k = k0 + tx;
    float v = tile[tx][ty + r];
    size_t o = (size_t)n * Kpad + k;
    f16 h = (f16)v;
    BtH[o] = h;
    BtL[o] = (f16)(v - (float)h);
  }
}

// Bt_lstm [2048][1024]: cols 0-511 = Wih row n, cols 512-1023 = Whh row n (no transpose!)
__global__ void conv_lstmB(const float* __restrict__ Wih, const float* __restrict__ Whh,
                           f16* __restrict__ H, f16* __restrict__ L) {
  uint32_t idx = blockIdx.x * 256u + threadIdx.x;  // 2048*1024
  uint32_t n = idx >> 10, k = idx & 1023u;
  float v = (k < 512u) ? Wih[(size_t)n * 512 + k] : Whh[(size_t)n * 512 + (k - 512u)];
  f16 h = (f16)v;
  H[idx] = h;
  L[idx] = (f16)(v - (float)h);
}

// h0 -> A_lstm cols 512..1023
__global__ void conv_h0(const float* __restrict__ h0, f16* __restrict__ H, f16* __restrict__ L) {
  uint32_t idx = blockIdx.x * 256u + threadIdx.x;  // 4096*512
  uint32_t b = idx >> 9, j = idx & 511u;
  float v = h0[idx];
  size_t o = (size_t)b * 1024 + 512 + j;
  f16 h = (f16)v;
  H[o] = h;
  L[o] = (f16)(v - (float)h);
}

// LSTM pointwise: gates [4096][2048] (i,f,g,o) -> z hi/lo into zcat (ld 576)
__global__ void lstm_pointwise(const float* __restrict__ gates, const float* __restrict__ c0,
                               f16* __restrict__ zH, f16* __restrict__ zL) {
  uint32_t idx = blockIdx.x * 256u + threadIdx.x;  // 4096*512
  uint32_t b = idx >> 9, n = idx & 511u;
  const float* g = gates + (size_t)b * 2048;
  float gi = g[n], gf = g[512 + n], gg = g[1024 + n], go = g[1536 + n];
  float si = 1.f / (1.f + expf(-gi));
  float sf = 1.f / (1.f + expf(-gf));
  float so = 1.f / (1.f + expf(-go));
  float c = sf * c0[idx] + si * tanhf(gg);
  float z = so * tanhf(c);
  size_t o = (size_t)b * 576 + n;
  f16 h = (f16)z;
  zH[o] = h;
  zL[o] = (f16)(z - (float)h);
}

// init: zero zcat pad cols 513..575 (both buffers), ws_logp, ws_entropy
__global__ void init_ws(f16* zAH, f16* zAL, f16* zBH, f16* zBL,
                        float* wsLogp, float* wsEnt) {
  uint32_t idx = blockIdx.x * 256u + threadIdx.x;
  if (idx < 4096u * 63u) {
    uint32_t b = idx / 63u, c = 513u + idx - b * 63u;
    size_t o = (size_t)b * 576 + c;
    zAH[o] = (f16)0.f; zAL[o] = (f16)0.f; zBH[o] = (f16)0.f; zBL[o] = (f16)0.f;
  }
  if (idx < 4096u) wsLogp[idx] = 0.f;
  if (idx == 0) *wsEnt = 0.f;
}

__device__ inline double shfl_xor_dbl(double v, int m) {
  union { double d; int i[2]; } u;
  u.d = v;
  u.i[0] = __shfl_xor(u.i[0], m);
  u.i[1] = __shfl_xor(u.i[1], m);
  return u.d;
}

// one wave per batch row; 64 lanes <-> 64 categories
__global__ void sample_head(const float* __restrict__ logits,  // ld 128
                            uint32_t sk0, uint32_t sk1, int head, int partitionable,
                            float* __restrict__ outAct,
                            f16* __restrict__ zH, f16* __restrict__ zL,  // current zcat
                            float* __restrict__ wsLogp, float* __restrict__ wsEnt) {
  int wave = threadIdx.x >> 6, lane = threadIdx.x & 63;
  int b = blockIdx.x * 4 + wave;
  float l = logits[(size_t)b * 128 + lane];

  // ---- gumbel bits per (b,lane) ----
  uint32_t i = (uint32_t)b * 64u + (uint32_t)lane;
  uint32_t bits;
  if (partitionable) {
    uint32_t o0, o1;
    tf2x32(sk0, sk1, 0u, i, o0, o1);
    bits = o0 ^ o1;
  } else {
    const uint32_t H = 131072u;  // (4096*64)/2
    uint32_t c0, c1, o0, o1;
    int pick;
    if (i < H) { c0 = i; c1 = i + H; pick = 0; }
    else       { c0 = i - H; c1 = i; pick = 1; }
    tf2x32(sk0, sk1, c0, c1, o0, o1);
    bits = pick ? o1 : o0;
  }
  uint32_t ub = (bits >> 9) | 0x3f800000u;
  float u;
  __builtin_memcpy(&u, &ub, 4);
  u -= 1.0f;
  if (u == 0.0f) u = 1.17549435e-38f;
  double gum = -log(-log((double)u));
  double s = (double)l + gum;

  // ---- argmax (first index wins on ties) ----
  int bi = lane;
  double bv = s;
#pragma unroll
  for (int off = 1; off < 64; off <<= 1) {
    double ov = shfl_xor_dbl(bv, off);
    int oi = __shfl_xor(bi, off);
    if (ov > bv || (ov == bv && oi < bi)) { bv = ov; bi = oi; }
  }
  int act = bi;

  // ---- softmax stats ----
  float m = l;
#pragma unroll
  for (int off = 1; off < 64; off <<= 1) m = fmaxf(m, __shfl_xor(m, off));
  float e = expf(l - m);
  float S = e, D = e * l;
#pragma unroll
  for (int off = 1; off < 64; off <<= 1) {
    S += __shfl_xor(S, off);
    D += __shfl_xor(D, off);
  }
  float M = m + logf(S);
  float Hrow = M - D / S;
  float l_act = __shfl(l, act);

  if (lane == 0) {
    outAct[(size_t)b * 8 + head] = (float)act;
    wsLogp[b] += (l_act - M);
    size_t zo = (size_t)b * 576 + 512;
    zH[zo] = (f16)act;  // act <= 63, exact in fp16
    zL[zo] = (f16)0.f;
  }
  __shared__ float hs[4];
  if (lane == 0) hs[wave] = Hrow;
  __syncthreads();
  if (threadIdx.x == 0) atomicAdd(wsEnt, hs[0] + hs[1] + hs[2] + hs[3]);
}

__global__ void finalize_out(const float* __restrict__ wsEnt, const float* __restrict__ wsLogp,
                             float* __restrict__ out) {
  uint32_t idx = blockIdx.x * 256u + threadIdx.x;
  if (idx == 0) out[32768] = *wsEnt;
  if (idx < 4096u) out[32769 + idx] = wsLogp[idx];
}

// ---------------- host ----------------
extern "C" void kernel_launch(void* const* d_in, const int* in_sizes, int n_in,
                              void* d_out, int out_size, void* d_ws, size_t ws_size,
                              hipStream_t stream) {
  (void)in_sizes; (void)out_size; (void)ws_size;
  const float* actual = (const float*)d_in[0];
  const float* object = (const float*)d_in[1];
  const float* lastA = (const float*)d_in[2];
  const int* ep = (const int*)d_in[3];
  const float* W1 = (const float*)d_in[4];
  const float* b1 = (const float*)d_in[5];
  const float* W2 = (const float*)d_in[6];
  const float* b2 = (const float*)d_in[7];
  const float* W3 = (const float*)d_in[8];
  const float* b3 = (const float*)d_in[9];
  const float* Wih = (const float*)d_in[10];
  const float* Whh = (const float*)d_in[11];
  const float* bih = (const float*)d_in[12];
  const float* bhh = (const float*)d_in[13];
  const float* h0 = (const float*)d_in[14];
  const float* c0 = (const float*)d_in[15];
  const float* dW1 = (const float*)d_in[16];
  const float* db1 = (const float*)d_in[17];
  const float* headW[8];
  const float* headb[8];
  const float *dWo, *dbo;
  if (n_in >= 36) {
    for (int h = 0; h < 8; ++h) headW[h] = (const float*)d_in[18 + h];
    for (int h = 0; h < 8; ++h) headb[h] = (const float*)d_in[26 + h];
    dWo = (const float*)d_in[34];
    dbo = (const float*)d_in[35];
  } else {  // tuples passed as single flattened blobs
    const float* hw = (const float*)d_in[18];
    const float* hb = (const float*)d_in[19];
    for (int h = 0; h < 8; ++h) { headW[h] = hw + (size_t)h * 256 * 64; headb[h] = hb + (size_t)h * 64; }
    dWo = (const float*)d_in[20];
    dbo = (const float*)d_in[21];
  }

  // dims (padded)
  constexpr int Bq = 4096;
  constexpr int K1 = 9280, N1 = 3584, N1r = 3518;
  constexpr int K2 = 3584, N2 = 1408, N2r = 1342;
  constexpr int K3 = 1408, N3 = 512;
  constexpr int KL = 1024, NL = 2048;
  constexpr int KD1 = 512, ND1 = 256;
  constexpr int KH = 256, NHp = 128;
  constexpr int KDO = 576, NDO = 512;

  uint8_t* w = (uint8_t*)d_ws;
  size_t off = 0;
  auto alloc = [&](size_t bytes) -> void* {
    off = (off + 1023) & ~(size_t)1023;
    void* p = w + off;
    off += bytes;
    return p;
  };
  // fixed region
  f16* A1h = (f16*)alloc((size_t)Bq * K1 * 2);
  f16* A1l = (f16*)alloc((size_t)Bq * K1 * 2);
  size_t fixedReuseEnd = off;  // pool aliases [0, end of A1) which is dead after GEMM1
  f16* Bt1h = (f16*)alloc((size_t)N1 * K1 * 2);
  f16* Bt1l = (f16*)alloc((size_t)N1 * K1 * 2);
  f16* x1h = (f16*)alloc((size_t)Bq * K2 * 2);
  f16* x1l = (f16*)alloc((size_t)Bq * K2 * 2);
  f16* Bt2h = (f16*)alloc((size_t)N2 * K2 * 2);
  f16* Bt2l = (f16*)alloc((size_t)N2 * K2 * 2);
  // pool region aliases A1 (dead after GEMM1); everything below fits in 152MB
  size_t poff = 0;
  auto palloc = [&](size_t bytes) -> void* {
    poff = (poff + 1023) & ~(size_t)1023;
    void* p = w + poff;
    poff += bytes;
    return p;
  };
  f16* x2h = (f16*)palloc((size_t)Bq * K3 * 2);
  f16* x2l = (f16*)palloc((size_t)Bq * K3 * 2);
  f16* Bt3h = (f16*)palloc((size_t)N3 * K3 * 2);
  f16* Bt3l = (f16*)palloc((size_t)N3 * K3 * 2);
  f16* ALh = (f16*)palloc((size_t)Bq * KL * 2);
  f16* ALl = (f16*)palloc((size_t)Bq * KL * 2);
  f16* BLh = (f16*)palloc((size_t)NL * KL * 2);
  f16* BLl = (f16*)palloc((size_t)NL * KL * 2);
  float* gates = (float*)palloc((size_t)Bq * NL * 4);
  f16* zAH = (f16*)palloc((size_t)Bq * 576 * 2);
  f16* zAL = (f16*)palloc((size_t)Bq * 576 * 2);
  f16* zBH = (f16*)palloc((size_t)Bq * 576 * 2);
  f16* zBL = (f16*)palloc((size_t)Bq * 576 * 2);
  f16* Btd1h = (f16*)palloc((size_t)ND1 * KD1 * 2);
  f16* Btd1l = (f16*)palloc((size_t)ND1 * KD1 * 2);
  f16* z1h = (f16*)palloc((size_t)Bq * ND1 * 2);
  f16* z1l = (f16*)palloc((size_t)Bq * ND1 * 2);
  f16* Bthh = (f16*)palloc((size_t)8 * NHp * KH * 2);
  f16* Bthl = (f16*)palloc((size_t)8 * NHp * KH * 2);
  float* logitsF = (float*)palloc((size_t)Bq * 128 * 4);
  f16* Btdoh = (f16*)palloc((size_t)NDO * KDO * 2);
  f16* Btdol = (f16*)palloc((size_t)NDO * KDO * 2);
  float* wsLogp = (float*)palloc((size_t)Bq * 4);
  float* wsEnt = (float*)palloc(64);
  (void)fixedReuseEnd;

  // ---- subkeys (host, depends only on seed 42) ----
  uint32_t k0 = 0u, k1 = 42u;
  uint32_t sk[8][2];
  for (int h = 0; h < 8; ++h) {
    if (kPartitionable) {
      uint32_t a0, a1, b0v, b1v;
      tf2x32(k0, k1, 0u, 0u, a0, a1);   // child 0 -> new key
      tf2x32(k0, k1, 0u, 1u, b0v, b1v); // child 1 -> subkey
      sk[h][0] = b0v; sk[h][1] = b1v;
      k0 = a0; k1 = a1;
    } else {
      uint32_t a0, a1, b0v, b1v;
      tf2x32(k0, k1, 0u, 2u, a0, a1);
      tf2x32(k0, k1, 1u, 3u, b0v, b1v);
      sk[h][0] = a1; sk[h][1] = b1v;
      k0 = a0; k1 = b0v;
    }
  }

  dim3 blk(256);
  dim3 tblk(32, 8);

  // 1) conversions into fixed region
  conv_feats<<<(4096u * 9280u + 255) / 256, blk, 0, stream>>>(actual, object, lastA, ep, A1h, A1l);
  convT_kernel<<<dim3(K1 / 32, N1 / 32), tblk, 0, stream>>>(W1, 9225, 3518, Bt1h, Bt1l, K1);
  convT_kernel<<<dim3(K2 / 32, N2 / 32), tblk, 0, stream>>>(W2, 3518, 1342, Bt2h, Bt2l, K2);

  // 2) GEMM1: x1 = relu(feats @ W1 + b1)
  gemm_split<128, 128><<<dim3(Bq / 128, N1 / 128), blk, 0, stream>>>(
      A1h, A1l, K1, Bt1h, Bt1l, K1, K1, b1, nullptr, N1r, 1, 0, nullptr, x1h, x1l, K2);

  // 3) pool conversions (A1 now dead)
  init_ws<<<(4096u * 63u + 255) / 256, blk, 0, stream>>>(zAH, zAL, zBH, zBL, wsLogp, wsEnt);
  convT_kernel<<<dim3(K3 / 32, N3 / 32), tblk, 0, stream>>>(W3, 1342, 512, Bt3h, Bt3l, K3);
  conv_lstmB<<<(2048u * 1024u) / 256, blk, 0, stream>>>(Wih, Whh, BLh, BLl);
  conv_h0<<<(4096u * 512u) / 256, blk, 0, stream>>>(h0, ALh, ALl);
  convT_kernel<<<dim3(KD1 / 32, ND1 / 32), tblk, 0, stream>>>(dW1, 512, 256, Btd1h, Btd1l, KD1);
  convT_kernel<<<dim3(KDO / 32, NDO / 32), tblk, 0, stream>>>(dWo, 513, 512, Btdoh, Btdol, KDO);
  for (int h = 0; h < 8; ++h)
    convT_kernel<<<dim3(KH / 32, NHp / 32), tblk, 0, stream>>>(
        headW[h], 256, 64, Bthh + (size_t)h * NHp * KH, Bthl + (size_t)h * NHp * KH, KH);

  // 4) GEMM2: x2 = relu(x1 @ W2 + b2)
  gemm_split<128, 128><<<dim3(Bq / 128, N2 / 128), blk, 0, stream>>>(
      x1h, x1l, K2, Bt2h, Bt2l, K2, K2, b2, nullptr, N2r, 1, 0, nullptr, x2h, x2l, K3);
  // 5) GEMM3: x3 = relu(x2 @ W3 + b3) -> A_lstm cols 0..511
  gemm_split<128, 128><<<dim3(Bq / 128, N3 / 128), blk, 0, stream>>>(
      x2h, x2l, K3, Bt3h, Bt3l, K3, K3, b3, nullptr, N3, 1, 0, nullptr, ALh, ALl, KL);
  // 6) gates = [x3|h0] @ [Wih^T;Whh^T] + bih + bhh
  gemm_split<128, 128><<<dim3(Bq / 128, NL / 128), blk, 0, stream>>>(
      ALh, ALl, KL, BLh, BLl, KL, KL, bih, bhh, NL, 0, 1, gates, nullptr, nullptr, NL);
  // 7) LSTM pointwise -> z into zcatA
  lstm_pointwise<<<(4096u * 512u) / 256, blk, 0, stream>>>(gates, c0, zAH, zAL);

  // 8) decoder
  for (int h = 0; h < 8; ++h) {
    f16* curH = (h & 1) ? zBH : zAH;
    f16* curL = (h & 1) ? zBL : zAL;
    f16* nxtH = (h & 1) ? zAH : zBH;
    f16* nxtL = (h & 1) ? zAL : zBL;
    // z1 = relu(z @ dW1 + db1)
    gemm_split<64, 64><<<dim3(Bq / 64, ND1 / 64), blk, 0, stream>>>(
        curH, curL, 576, Btd1h, Btd1l, KD1, KD1, db1, nullptr, ND1, 1, 0, nullptr, z1h, z1l, ND1);
    // logits = z1 @ Wk + bk
    gemm_split<64, 64><<<dim3(Bq / 64, NHp / 64), blk, 0, stream>>>(
        z1h, z1l, ND1, Bthh + (size_t)h * NHp * KH, Bthl + (size_t)h * NHp * KH, KH, KH,
        headb[h], nullptr, 64, 0, 1, logitsF, nullptr, nullptr, 128);
    // sample + entropy + logp; writes act into cur zcat col 512
    sample_head<<<Bq / 4, blk, 0, stream>>>(logitsF, sk[h][0], sk[h][1], h, kPartitionable,
                                            (float*)d_out, curH, curL, wsLogp, wsEnt);
    // z = relu([z|act] @ dWo + dbo) -> next zcat cols 0..511
    gemm_split<64, 64><<<dim3(Bq / 64, NDO / 64), blk, 0, stream>>>(
        curH, curL, 576, Btdoh, Btdol, KDO, KDO, dbo, nullptr, NDO, 1, 0, nullptr, nxtH, nxtL, 576);
  }
  // 9) entropy + logp to out
  finalize_out<<<(4097 + 255) / 256, blk, 0, stream>>>(wsEnt, wsLogp, (float*)d_out);
}

// Round 2
// 2023.557 us; speedup vs baseline: 1.1418x; 1.1418x over previous
//
#include <hip/hip_runtime.h>
#include <cstdint>
#include <cstring>

typedef _Float16 f16;
typedef _Float16 f16x8 __attribute__((ext_vector_type(8)));
typedef float f32x4 __attribute__((ext_vector_type(4)));

// ---- JAX threefry scheme: 1 = partitionable (jax >= 0.4.36 default), 0 = original
static constexpr int kPartitionable = 1;

// ---------------- Threefry-2x32 (host + device) ----------------
__host__ __device__ inline void tf2x32(uint32_t k0, uint32_t k1,
                                       uint32_t x0, uint32_t x1,
                                       uint32_t& o0, uint32_t& o1) {
  uint32_t ks[3] = {k0, k1, k0 ^ k1 ^ 0x1BD11BDAu};
  uint32_t v0 = x0 + ks[0], v1 = x1 + ks[1];
  const int r0[4] = {13, 15, 26, 6};
  const int r1[4] = {17, 29, 16, 24};
  for (int g = 0; g < 5; ++g) {
    const int* rr = (g & 1) ? r1 : r0;
    for (int j = 0; j < 4; ++j) {
      v0 += v1;
      v1 = (v1 << rr[j]) | (v1 >> (32 - rr[j]));
      v1 ^= v0;
    }
    v0 += ks[(g + 1) % 3];
    v1 += ks[(g + 2) % 3] + (uint32_t)(g + 1);
  }
  o0 = v0; o1 = v1;
}

// ---------------- split-fp16 MFMA GEMM ----------------
// C[m][n] = sum_k A[m][k]*Bt[n][k], A/Bt given as (hi,lo) fp16 pairs.
// 3 MFMAs per fragment pair: hi*hi + hi*lo + lo*hi (fp32 accumulate).
// LDS row stride padded 64->72 f16 (+16B): fragment-read bank =
// (fr*4 + q8/2 + kk/2)%32 -> 2-way aliasing (free on CDNA4) instead of the
// unpadded 16-way same-bank pileup (row stride 128B == 32 banks).
// Epilogue: +bias1(+bias2), optional relu; writes f32 OR fp16 (hi,lo) split.
template <int BM, int BN>
__global__ __launch_bounds__(256, 2) void gemm_split(
    const f16* __restrict__ Ah, const f16* __restrict__ Al, int lda,
    const f16* __restrict__ Bh, const f16* __restrict__ Bl, int ldb,
    int K,
    const float* __restrict__ bias1, const float* __restrict__ bias2,
    int nReal, int relu, int writeF32,
    float* __restrict__ outF, f16* __restrict__ outH, f16* __restrict__ outL,
    int ldo) {
  constexpr int BK = 64;
  constexpr int BKP = BK + 8;  // padded LDS stride (144 B = 9 x 16 B, keeps uint4 alignment)
  constexpr int TM = BM / 32;  // 16x16 tiles per wave along M
  constexpr int TN = BN / 32;
  static_assert(BM == BN, "square tiles only");
  __shared__ f16 sAh[BM * BKP];
  __shared__ f16 sAl[BM * BKP];
  __shared__ f16 sBh[BN * BKP];
  __shared__ f16 sBl[BN * BKP];

  const int tid = threadIdx.x;
  const int wave = tid >> 6;
  const int lane = tid & 63;
  const int wm = wave & 1, wn = wave >> 1;
  const int m0 = blockIdx.x * BM;
  const int n0 = blockIdx.y * BN;

  f32x4 acc[TM][TN];
  const f32x4 zero = {0.f, 0.f, 0.f, 0.f};
#pragma unroll
  for (int i = 0; i < TM; ++i)
#pragma unroll
    for (int j = 0; j < TN; ++j) acc[i][j] = zero;

  // staging: wave 0->sAh, 1->sAl, 2->sBh, 3->sBl   (BM==BN so same shape)
  const f16* src;
  f16* dst;
  int ld, base;
  if (wave == 0)      { src = Ah; dst = sAh; ld = lda; base = m0; }
  else if (wave == 1) { src = Al; dst = sAl; ld = lda; base = m0; }
  else if (wave == 2) { src = Bh; dst = sBh; ld = ldb; base = n0; }
  else                { src = Bl; dst = sBl; ld = ldb; base = n0; }
  constexpr int NITER = (BM * 8) / 64;  // 16B chunks per lane per tile

  for (int k0 = 0; k0 < K; k0 += BK) {
    __syncthreads();
#pragma unroll
    for (int j = 0; j < NITER; ++j) {
      int c = j * 64 + lane;
      int row = c >> 3, col = c & 7;
      const uint4* g = (const uint4*)(src + (size_t)(base + row) * ld + k0) + col;
      uint4 v = *g;
      ((uint4*)dst)[row * 9 + col] = v;  // BKP*2/16 == 9 uint4 per row
    }
    __syncthreads();
#pragma unroll
    for (int kk = 0; kk < BK; kk += 32) {
      const int fr = lane & 15;
      const int q8 = (lane >> 4) * 8;
      f16x8 aH[TM], aL[TM], bH[TN], bL[TN];
#pragma unroll
      for (int i = 0; i < TM; ++i) {
        int off = (wm * (BM / 2) + i * 16 + fr) * BKP + kk + q8;
        aH[i] = *(const f16x8*)&sAh[off];
        aL[i] = *(const f16x8*)&sAl[off];
      }
#pragma unroll
      for (int j = 0; j < TN; ++j) {
        int off = (wn * (BN / 2) + j * 16 + fr) * BKP + kk + q8;
        bH[j] = *(const f16x8*)&sBh[off];
        bL[j] = *(const f16x8*)&sBl[off];
      }
#pragma unroll
      for (int i = 0; i < TM; ++i)
#pragma unroll
        for (int j = 0; j < TN; ++j) {
          acc[i][j] = __builtin_amdgcn_mfma_f32_16x16x32_f16(aH[i], bH[j], acc[i][j], 0, 0, 0);
          acc[i][j] = __builtin_amdgcn_mfma_f32_16x16x32_f16(aH[i], bL[j], acc[i][j], 0, 0, 0);
          acc[i][j] = __builtin_amdgcn_mfma_f32_16x16x32_f16(aL[i], bH[j], acc[i][j], 0, 0, 0);
        }
    }
  }
  // epilogue: C/D layout col=lane&15, row=(lane>>4)*4+reg (m89/m91 verified)
  const int rq = lane >> 4, cl = lane & 15;
#pragma unroll
  for (int i = 0; i < TM; ++i)
#pragma unroll
    for (int j = 0; j < TN; ++j)
#pragma unroll
      for (int r = 0; r < 4; ++r) {
        int row = m0 + wm * (BM / 2) + i * 16 + rq * 4 + r;
        int col = n0 + wn * (BN / 2) + j * 16 + cl;
        float v = acc[i][j][r];
        if (col < nReal) {
          if (bias1) v += bias1[col];
          if (bias2) v += bias2[col];
          if (relu) v = fmaxf(v, 0.f);
        } else {
          v = 0.f;
        }
        size_t o = (size_t)row * ldo + col;
        if (writeF32) {
          outF[o] = v;
        } else {
          f16 h = (f16)v;
          outH[o] = h;
          outL[o] = (f16)(v - (float)h);
        }
      }
}

// ---------------- conversion kernels ----------------
// feats = [actual | objective | last_action | ep | zeros]  -> hi/lo fp16 [4096][9280]
__global__ void conv_feats(const float* __restrict__ A, const float* __restrict__ O,
                           const float* __restrict__ LA, const int* __restrict__ EP,
                           f16* __restrict__ H, f16* __restrict__ L) {
  uint32_t idx = blockIdx.x * 256u + threadIdx.x;
  const uint32_t total = 4096u * 9280u;
  if (idx >= total) return;
  uint32_t b = idx / 9280u, c = idx - b * 9280u;
  float v;
  if (c < 4608u) v = A[(size_t)b * 4608 + c];
  else if (c < 9216u) v = O[(size_t)b * 4608 + (c - 4608u)];
  else if (c < 9224u) v = LA[(size_t)b * 8 + (c - 9216u)];
  else if (c == 9224u) v = (float)EP[0];
  else v = 0.f;
  f16 h = (f16)v;
  H[idx] = h;
  L[idx] = (f16)(v - (float)h);
}

// W [Kreal][Nreal] (row stride Nreal) -> Bt hi/lo [Npad][Kpad] with Bt[n][k]=W[k][n]
__global__ void convT_kernel(const float* __restrict__ W, int Kreal, int Nreal,
                             f16* __restrict__ BtH, f16* __restrict__ BtL, int Kpad) {
  __shared__ float tile[32][33];
  int k0 = blockIdx.x * 32, n0 = blockIdx.y * 32;
  int tx = threadIdx.x, ty = threadIdx.y;  // 32 x 8
  for (int r = 0; r < 32; r += 8) {
    int k = k0 + ty + r, n = n0 + tx;
    float v = (k < Kreal && n < Nreal) ? W[(size_t)k * Nreal + n] : 0.f;
    tile[ty + r][tx] = v;
  }
  __syncthreads();
  for (int r = 0; r < 32; r += 8) {
    int n = n0 + ty + r, k = k0 + tx;
    float v = tile[tx][ty + r];
    size_t o = (size_t)n * Kpad + k;
    f16 h = (f16)v;
    BtH[o] = h;
    BtL[o] = (f16)(v - (float)h);
  }
}

// Bt_lstm [2048][1024]: cols 0-511 = Wih row n, cols 512-1023 = Whh row n (no transpose!)
__global__ void conv_lstmB(const float* __restrict__ Wih, const float* __restrict__ Whh,
                           f16* __restrict__ H, f16* __restrict__ L) {
  uint32_t idx = blockIdx.x * 256u + threadIdx.x;  // 2048*1024
  uint32_t n = idx >> 10, k = idx & 1023u;
  float v = (k < 512u) ? Wih[(size_t)n * 512 + k] : Whh[(size_t)n * 512 + (k - 512u)];
  f16 h = (f16)v;
  H[idx] = h;
  L[idx] = (f16)(v - (float)h);
}

// h0 -> A_lstm cols 512..1023
__global__ void conv_h0(const float* __restrict__ h0, f16* __restrict__ H, f16* __restrict__ L) {
  uint32_t idx = blockIdx.x * 256u + threadIdx.x;  // 4096*512
  uint32_t b = idx >> 9, j = idx & 511u;
  float v = h0[idx];
  size_t o = (size_t)b * 1024 + 512 + j;
  f16 h = (f16)v;
  H[o] = h;
  L[o] = (f16)(v - (float)h);
}

// LSTM pointwise: gates [4096][2048] (i,f,g,o) -> z hi/lo into zcat (ld 576)
__global__ void lstm_pointwise(const float* __restrict__ gates, const float* __restrict__ c0,
                               f16* __restrict__ zH, f16* __restrict__ zL) {
  uint32_t idx = blockIdx.x * 256u + threadIdx.x;  // 4096*512
  uint32_t b = idx >> 9, n = idx & 511u;
  const float* g = gates + (size_t)b * 2048;
  float gi = g[n], gf = g[512 + n], gg = g[1024 + n], go = g[1536 + n];
  float si = 1.f / (1.f + expf(-gi));
  float sf = 1.f / (1.f + expf(-gf));
  float so = 1.f / (1.f + expf(-go));
  float c = sf * c0[idx] + si * tanhf(gg);
  float z = so * tanhf(c);
  size_t o = (size_t)b * 576 + n;
  f16 h = (f16)z;
  zH[o] = h;
  zL[o] = (f16)(z - (float)h);
}

// init: zero zcat pad cols 513..575 (both buffers), ws_logp, ws_entropy
__global__ void init_ws(f16* zAH, f16* zAL, f16* zBH, f16* zBL,
                        float* wsLogp, float* wsEnt) {
  uint32_t idx = blockIdx.x * 256u + threadIdx.x;
  if (idx < 4096u * 63u) {
    uint32_t b = idx / 63u, c = 513u + idx - b * 63u;
    size_t o = (size_t)b * 576 + c;
    zAH[o] = (f16)0.f; zAL[o] = (f16)0.f; zBH[o] = (f16)0.f; zBL[o] = (f16)0.f;
  }
  if (idx < 4096u) wsLogp[idx] = 0.f;
  if (idx == 0) *wsEnt = 0.f;
}

__device__ inline double shfl_xor_dbl(double v, int m) {
  union { double d; int i[2]; } u;
  u.d = v;
  u.i[0] = __shfl_xor(u.i[0], m);
  u.i[1] = __shfl_xor(u.i[1], m);
  return u.d;
}

// one wave per batch row; 64 lanes <-> 64 categories
__global__ void sample_head(const float* __restrict__ logits,  // ld 128
                            uint32_t sk0, uint32_t sk1, int head, int partitionable,
                            float* __restrict__ outAct,
                            f16* __restrict__ zH, f16* __restrict__ zL,  // current zcat
                            float* __restrict__ wsLogp, float* __restrict__ wsEnt) {
  int wave = threadIdx.x >> 6, lane = threadIdx.x & 63;
  int b = blockIdx.x * 4 + wave;
  float l = logits[(size_t)b * 128 + lane];

  // ---- gumbel bits per (b,lane) ----
  uint32_t i = (uint32_t)b * 64u + (uint32_t)lane;
  uint32_t bits;
  if (partitionable) {
    uint32_t o0, o1;
    tf2x32(sk0, sk1, 0u, i, o0, o1);
    bits = o0 ^ o1;
  } else {
    const uint32_t H = 131072u;  // (4096*64)/2
    uint32_t c0, c1, o0, o1;
    int pick;
    if (i < H) { c0 = i; c1 = i + H; pick = 0; }
    else       { c0 = i - H; c1 = i; pick = 1; }
    tf2x32(sk0, sk1, c0, c1, o0, o1);
    bits = pick ? o1 : o0;
  }
  uint32_t ub = (bits >> 9) | 0x3f800000u;
  float u;
  __builtin_memcpy(&u, &ub, 4);
  u -= 1.0f;
  if (u == 0.0f) u = 1.17549435e-38f;
  double gum = -log(-log((double)u));
  double s = (double)l + gum;

  // ---- argmax (first index wins on ties) ----
  int bi = lane;
  double bv = s;
#pragma unroll
  for (int off = 1; off < 64; off <<= 1) {
    double ov = shfl_xor_dbl(bv, off);
    int oi = __shfl_xor(bi, off);
    if (ov > bv || (ov == bv && oi < bi)) { bv = ov; bi = oi; }
  }
  int act = bi;

  // ---- softmax stats ----
  float m = l;
#pragma unroll
  for (int off = 1; off < 64; off <<= 1) m = fmaxf(m, __shfl_xor(m, off));
  float e = expf(l - m);
  float S = e, D = e * l;
#pragma unroll
  for (int off = 1; off < 64; off <<= 1) {
    S += __shfl_xor(S, off);
    D += __shfl_xor(D, off);
  }
  float M = m + logf(S);
  float Hrow = M - D / S;
  float l_act = __shfl(l, act);

  if (lane == 0) {
    outAct[(size_t)b * 8 + head] = (float)act;
    wsLogp[b] += (l_act - M);
    size_t zo = (size_t)b * 576 + 512;
    zH[zo] = (f16)act;  // act <= 63, exact in fp16
    zL[zo] = (f16)0.f;
  }
  __shared__ float hs[4];
  if (lane == 0) hs[wave] = Hrow;
  __syncthreads();
  if (threadIdx.x == 0) atomicAdd(wsEnt, hs[0] + hs[1] + hs[2] + hs[3]);
}

__global__ void finalize_out(const float* __restrict__ wsEnt, const float* __restrict__ wsLogp,
                             float* __restrict__ out) {
  uint32_t idx = blockIdx.x * 256u + threadIdx.x;
  if (idx == 0) out[32768] = *wsEnt;
  if (idx < 4096u) out[32769 + idx] = wsLogp[idx];
}

// ---------------- host ----------------
extern "C" void kernel_launch(void* const* d_in, const int* in_sizes, int n_in,
                              void* d_out, int out_size, void* d_ws, size_t ws_size,
                              hipStream_t stream) {
  (void)in_sizes; (void)out_size; (void)ws_size;
  const float* actual = (const float*)d_in[0];
  const float* object = (const float*)d_in[1];
  const float* lastA = (const float*)d_in[2];
  const int* ep = (const int*)d_in[3];
  const float* W1 = (const float*)d_in[4];
  const float* b1 = (const float*)d_in[5];
  const float* W2 = (const float*)d_in[6];
  const float* b2 = (const float*)d_in[7];
  const float* W3 = (const float*)d_in[8];
  const float* b3 = (const float*)d_in[9];
  const float* Wih = (const float*)d_in[10];
  const float* Whh = (const float*)d_in[11];
  const float* bih = (const float*)d_in[12];
  const float* bhh = (const float*)d_in[13];
  const float* h0 = (const float*)d_in[14];
  const float* c0 = (const float*)d_in[15];
  const float* dW1 = (const float*)d_in[16];
  const float* db1 = (const float*)d_in[17];
  const float* headW[8];
  const float* headb[8];
  const float *dWo, *dbo;
  if (n_in >= 36) {
    for (int h = 0; h < 8; ++h) headW[h] = (const float*)d_in[18 + h];
    for (int h = 0; h < 8; ++h) headb[h] = (const float*)d_in[26 + h];
    dWo = (const float*)d_in[34];
    dbo = (const float*)d_in[35];
  } else {  // tuples passed as single flattened blobs
    const float* hw = (const float*)d_in[18];
    const float* hb = (const float*)d_in[19];
    for (int h = 0; h < 8; ++h) { headW[h] = hw + (size_t)h * 256 * 64; headb[h] = hb + (size_t)h * 64; }
    dWo = (const float*)d_in[20];
    dbo = (const float*)d_in[21];
  }

  // dims (padded)
  constexpr int Bq = 4096;
  constexpr int K1 = 9280, N1 = 3584, N1r = 3518;
  constexpr int K2 = 3584, N2 = 1408, N2r = 1342;
  constexpr int K3 = 1408, N3 = 512;
  constexpr int KL = 1024, NL = 2048;
  constexpr int KD1 = 512, ND1 = 256;
  constexpr int KH = 256, NHp = 128;
  constexpr int KDO = 576, NDO = 512;

  uint8_t* w = (uint8_t*)d_ws;
  size_t off = 0;
  auto alloc = [&](size_t bytes) -> void* {
    off = (off + 1023) & ~(size_t)1023;
    void* p = w + off;
    off += bytes;
    return p;
  };
  // fixed region
  f16* A1h = (f16*)alloc((size_t)Bq * K1 * 2);
  f16* A1l = (f16*)alloc((size_t)Bq * K1 * 2);
  size_t fixedReuseEnd = off;  // pool aliases [0, end of A1) which is dead after GEMM1
  f16* Bt1h = (f16*)alloc((size_t)N1 * K1 * 2);
  f16* Bt1l = (f16*)alloc((size_t)N1 * K1 * 2);
  f16* x1h = (f16*)alloc((size_t)Bq * K2 * 2);
  f16* x1l = (f16*)alloc((size_t)Bq * K2 * 2);
  f16* Bt2h = (f16*)alloc((size_t)N2 * K2 * 2);
  f16* Bt2l = (f16*)alloc((size_t)N2 * K2 * 2);
  // pool region aliases A1 (dead after GEMM1); everything below fits in 152MB
  size_t poff = 0;
  auto palloc = [&](size_t bytes) -> void* {
    poff = (poff + 1023) & ~(size_t)1023;
    void* p = w + poff;
    poff += bytes;
    return p;
  };
  f16* x2h = (f16*)palloc((size_t)Bq * K3 * 2);
  f16* x2l = (f16*)palloc((size_t)Bq * K3 * 2);
  f16* Bt3h = (f16*)palloc((size_t)N3 * K3 * 2);
  f16* Bt3l = (f16*)palloc((size_t)N3 * K3 * 2);
  f16* ALh = (f16*)palloc((size_t)Bq * KL * 2);
  f16* ALl = (f16*)palloc((size_t)Bq * KL * 2);
  f16* BLh = (f16*)palloc((size_t)NL * KL * 2);
  f16* BLl = (f16*)palloc((size_t)NL * KL * 2);
  float* gates = (float*)palloc((size_t)Bq * NL * 4);
  f16* zAH = (f16*)palloc((size_t)Bq * 576 * 2);
  f16* zAL = (f16*)palloc((size_t)Bq * 576 * 2);
  f16* zBH = (f16*)palloc((size_t)Bq * 576 * 2);
  f16* zBL = (f16*)palloc((size_t)Bq * 576 * 2);
  f16* Btd1h = (f16*)palloc((size_t)ND1 * KD1 * 2);
  f16* Btd1l = (f16*)palloc((size_t)ND1 * KD1 * 2);
  f16* z1h = (f16*)palloc((size_t)Bq * ND1 * 2);
  f16* z1l = (f16*)palloc((size_t)Bq * ND1 * 2);
  f16* Bthh = (f16*)palloc((size_t)8 * NHp * KH * 2);
  f16* Bthl = (f16*)palloc((size_t)8 * NHp * KH * 2);
  float* logitsF = (float*)palloc((size_t)Bq * 128 * 4);
  f16* Btdoh = (f16*)palloc((size_t)NDO * KDO * 2);
  f16* Btdol = (f16*)palloc((size_t)NDO * KDO * 2);
  float* wsLogp = (float*)palloc((size_t)Bq * 4);
  float* wsEnt = (float*)palloc(64);
  (void)fixedReuseEnd;

  // ---- subkeys (host, depends only on seed 42) ----
  uint32_t k0 = 0u, k1 = 42u;
  uint32_t sk[8][2];
  for (int h = 0; h < 8; ++h) {
    if (kPartitionable) {
      uint32_t a0, a1, b0v, b1v;
      tf2x32(k0, k1, 0u, 0u, a0, a1);   // child 0 -> new key
      tf2x32(k0, k1, 0u, 1u, b0v, b1v); // child 1 -> subkey
      sk[h][0] = b0v; sk[h][1] = b1v;
      k0 = a0; k1 = a1;
    } else {
      uint32_t a0, a1, b0v, b1v;
      tf2x32(k0, k1, 0u, 2u, a0, a1);
      tf2x32(k0, k1, 1u, 3u, b0v, b1v);
      sk[h][0] = a1; sk[h][1] = b1v;
      k0 = a0; k1 = b0v;
    }
  }

  dim3 blk(256);
  dim3 tblk(32, 8);

  // 1) conversions into fixed region
  conv_feats<<<(4096u * 9280u + 255) / 256, blk, 0, stream>>>(actual, object, lastA, ep, A1h, A1l);
  convT_kernel<<<dim3(K1 / 32, N1 / 32), tblk, 0, stream>>>(W1, 9225, 3518, Bt1h, Bt1l, K1);
  convT_kernel<<<dim3(K2 / 32, N2 / 32), tblk, 0, stream>>>(W2, 3518, 1342, Bt2h, Bt2l, K2);

  // 2) GEMM1: x1 = relu(feats @ W1 + b1)
  gemm_split<128, 128><<<dim3(Bq / 128, N1 / 128), blk, 0, stream>>>(
      A1h, A1l, K1, Bt1h, Bt1l, K1, K1, b1, nullptr, N1r, 1, 0, nullptr, x1h, x1l, K2);

  // 3) pool conversions (A1 now dead)
  init_ws<<<(4096u * 63u + 255) / 256, blk, 0, stream>>>(zAH, zAL, zBH, zBL, wsLogp, wsEnt);
  convT_kernel<<<dim3(K3 / 32, N3 / 32), tblk, 0, stream>>>(W3, 1342, 512, Bt3h, Bt3l, K3);
  conv_lstmB<<<(2048u * 1024u) / 256, blk, 0, stream>>>(Wih, Whh, BLh, BLl);
  conv_h0<<<(4096u * 512u) / 256, blk, 0, stream>>>(h0, ALh, ALl);
  convT_kernel<<<dim3(KD1 / 32, ND1 / 32), tblk, 0, stream>>>(dW1, 512, 256, Btd1h, Btd1l, KD1);
  convT_kernel<<<dim3(KDO / 32, NDO / 32), tblk, 0, stream>>>(dWo, 513, 512, Btdoh, Btdol, KDO);
  for (int h = 0; h < 8; ++h)
    convT_kernel<<<dim3(KH / 32, NHp / 32), tblk, 0, stream>>>(
        headW[h], 256, 64, Bthh + (size_t)h * NHp * KH, Bthl + (size_t)h * NHp * KH, KH);

  // 4) GEMM2: x2 = relu(x1 @ W2 + b2)
  gemm_split<128, 128><<<dim3(Bq / 128, N2 / 128), blk, 0, stream>>>(
      x1h, x1l, K2, Bt2h, Bt2l, K2, K2, b2, nullptr, N2r, 1, 0, nullptr, x2h, x2l, K3);
  // 5) GEMM3: x3 = relu(x2 @ W3 + b3) -> A_lstm cols 0..511
  gemm_split<128, 128><<<dim3(Bq / 128, N3 / 128), blk, 0, stream>>>(
      x2h, x2l, K3, Bt3h, Bt3l, K3, K3, b3, nullptr, N3, 1, 0, nullptr, ALh, ALl, KL);
  // 6) gates = [x3|h0] @ [Wih^T;Whh^T] + bih + bhh
  gemm_split<128, 128><<<dim3(Bq / 128, NL / 128), blk, 0, stream>>>(
      ALh, ALl, KL, BLh, BLl, KL, KL, bih, bhh, NL, 0, 1, gates, nullptr, nullptr, NL);
  // 7) LSTM pointwise -> z into zcatA
  lstm_pointwise<<<(4096u * 512u) / 256, blk, 0, stream>>>(gates, c0, zAH, zAL);

  // 8) decoder
  for (int h = 0; h < 8; ++h) {
    f16* curH = (h & 1) ? zBH : zAH;
    f16* curL = (h & 1) ? zBL : zAL;
    f16* nxtH = (h & 1) ? zAH : zBH;
    f16* nxtL = (h & 1) ? zAL : zBL;
    // z1 = relu(z @ dW1 + db1)
    gemm_split<64, 64><<<dim3(Bq / 64, ND1 / 64), blk, 0, stream>>>(
        curH, curL, 576, Btd1h, Btd1l, KD1, KD1, db1, nullptr, ND1, 1, 0, nullptr, z1h, z1l, ND1);
    // logits = z1 @ Wk + bk
    gemm_split<64, 64><<<dim3(Bq / 64, NHp / 64), blk, 0, stream>>>(
        z1h, z1l, ND1, Bthh + (size_t)h * NHp * KH, Bthl + (size_t)h * NHp * KH, KH, KH,
        headb[h], nullptr, 64, 0, 1, logitsF, nullptr, nullptr, 128);
    // sample + entropy + logp; writes act into cur zcat col 512
    sample_head<<<Bq / 4, blk, 0, stream>>>(logitsF, sk[h][0], sk[h][1], h, kPartitionable,
                                            (float*)d_out, curH, curL, wsLogp, wsEnt);
    // z = relu([z|act] @ dWo + dbo) -> next zcat cols 0..511
    gemm_split<64, 64><<<dim3(Bq / 64, NDO / 64), blk, 0, stream>>>(
        curH, curL, 576, Btdoh, Btdol, KDO, KDO, dbo, nullptr, NDO, 1, 0, nullptr, nxtH, nxtL, 576);
  }
  // 9) entropy + logp to out
  finalize_out<<<(4097 + 255) / 256, blk, 0, stream>>>(wsEnt, wsLogp, (float*)d_out);
}